// Round 3
// baseline (1050.996 us; speedup 1.0000x reference)
//
#include <hip/hip_runtime.h>
#include <hip/hip_bf16.h>
#include <math.h>

typedef short s8v __attribute__((ext_vector_type(8)));
typedef float f32x4 __attribute__((ext_vector_type(4)));

__device__ __forceinline__ ushort f2bf(float f) {
    __hip_bfloat16 h = __float2bfloat16(f);
    return *reinterpret_cast<ushort*>(&h);
}
__device__ __forceinline__ float bf2f(ushort u) {
    return __uint_as_float(((unsigned)u) << 16);
}
__device__ __forceinline__ void gload16(const void* g, void* l) {
    __builtin_amdgcn_global_load_lds(
        (const __attribute__((address_space(1))) void*)g,
        (__attribute__((address_space(3))) void*)l, 16, 0, 0);
}

// ---------------- CSR build ----------------

__global__ __launch_bounds__(256)
void hist_kernel(const int* __restrict__ dst, int* __restrict__ cnt, int E) {
    int e = blockIdx.x * 256 + threadIdx.x;
    if (e < E) atomicAdd(&cnt[dst[e]], 1);
}

__global__ __launch_bounds__(1024)
void scan_kernel(const int* __restrict__ cnt, int* __restrict__ off, int n) {
    __shared__ int lds[1024];
    int t = threadIdx.x;
    int chunk = (n + 1023) >> 10;
    int begin = t * chunk;
    int end = min(begin + chunk, n);
    if (end < begin) end = begin;
    int s = 0;
    for (int i = begin; i < end; ++i) s += cnt[i];
    lds[t] = s;
    __syncthreads();
    for (int d = 1; d < 1024; d <<= 1) {
        int v = (t >= d) ? lds[t - d] : 0;
        __syncthreads();
        lds[t] += v;
        __syncthreads();
    }
    int pre = (t == 0) ? 0 : lds[t - 1];
    for (int i = begin; i < end; ++i) { off[i] = pre; pre += cnt[i]; }
    if (t == 1023) off[n] = pre;
}

__global__ __launch_bounds__(256)
void scatter_kernel(const int* __restrict__ src, const int* __restrict__ dst,
                    int* __restrict__ cur, const int* __restrict__ off,
                    int* __restrict__ csr, int E) {
    int e = blockIdx.x * 256 + threadIdx.x;
    if (e < E) {
        int d = dst[e];
        int pos = off[d] + atomicAdd(&cur[d], 1);
        csr[pos] = src[e];
    }
}

// ---------------- weight prep: transpose + hi/lo bf16 split ----------------

struct PrepArgs {
    const float* W[12];
    ushort* H[12];
    ushort* L[12];
    int end[12];
    int Kv[12];
    int nshift[12];
};

__global__ __launch_bounds__(256)
void prep_weights(PrepArgs a, int total) {
    int id = blockIdx.x * 256 + threadIdx.x;
    if (id >= total) return;
    int s = 0;
    #pragma unroll
    for (int i = 0; i < 12; ++i) if (id >= a.end[i]) s = i + 1;
    int base = (s == 0) ? 0 : a.end[s - 1];
    int e = id - base;
    int K = a.Kv[s];
    int Nmask = (1 << a.nshift[s]) - 1;
    int n = e & Nmask;
    int k = e >> a.nshift[s];
    float w = a.W[s][(size_t)k * (Nmask + 1) + n];
    ushort hi = f2bf(w);
    ushort lo = f2bf(w - bf2f(hi));
    a.H[s][(size_t)n * K + k] = hi;
    a.L[s][(size_t)n * K + k] = lo;
}

// ---------------- fp32 -> hi/lo bf16 plane split (for feat) ----------------

__global__ __launch_bounds__(256)
void split_f32_kernel(const float* __restrict__ X, ushort* __restrict__ H,
                      ushort* __restrict__ L, int total4) {
    int i = blockIdx.x * 256 + threadIdx.x;
    if (i >= total4) return;
    float4 v = *(const float4*)(X + (size_t)i * 4);
    ushort4 h, l;
    h.x = f2bf(v.x); l.x = f2bf(v.x - bf2f(h.x));
    h.y = f2bf(v.y); l.y = f2bf(v.y - bf2f(h.y));
    h.z = f2bf(v.z); l.z = f2bf(v.z - bf2f(h.z));
    h.w = f2bf(v.w); l.w = f2bf(v.w - bf2f(h.w));
    *(ushort4*)(H + (size_t)i * 4) = h;
    *(ushort4*)(L + (size_t)i * 4) = l;
}

// ---------------- per-dst online-softmax aggregation (hi/lo planes) ----------------

__global__ __launch_bounds__(256)
void sage_aggr_kernel(const ushort* __restrict__ XH, const ushort* __restrict__ XL,
                      const int* __restrict__ csr, const int* __restrict__ off,
                      ushort* __restrict__ OH, ushort* __restrict__ OL, int nN) {
    int node = blockIdx.x * 4 + (threadIdx.x >> 6);
    if (node >= nN) return;
    int c4 = (threadIdx.x & 63) * 4;
    int s0 = off[node], s1 = off[node + 1];
    float m0 = -INFINITY, m1 = -INFINITY, m2 = -INFINITY, m3 = -INFINITY;
    float se0 = 0, se1 = 0, se2 = 0, se3 = 0;
    float sm0 = 0, sm1 = 0, sm2 = 0, sm3 = 0;
#define ONLSTEP(vv, mm, ss, pp) { float nm = fmaxf(mm, vv); float r = __expf(mm - nm); \
    float p = __expf(vv - nm); ss = ss * r + p; pp = pp * r + p * (vv); mm = nm; }
    int j = s0;
    for (; j + 2 <= s1; j += 2) {
        int sa = csr[j], sb = csr[j + 1];
        size_t ba = (size_t)sa * 256 + c4, bb = (size_t)sb * 256 + c4;
        ushort4 ha = *(const ushort4*)(XH + ba);
        ushort4 la = *(const ushort4*)(XL + ba);
        ushort4 hb = *(const ushort4*)(XH + bb);
        ushort4 lb = *(const ushort4*)(XL + bb);
        float a0 = bf2f(ha.x) + bf2f(la.x), a1 = bf2f(ha.y) + bf2f(la.y);
        float a2 = bf2f(ha.z) + bf2f(la.z), a3 = bf2f(ha.w) + bf2f(la.w);
        float b0 = bf2f(hb.x) + bf2f(lb.x), b1 = bf2f(hb.y) + bf2f(lb.y);
        float b2 = bf2f(hb.z) + bf2f(lb.z), b3 = bf2f(hb.w) + bf2f(lb.w);
        ONLSTEP(a0, m0, se0, sm0) ONLSTEP(a1, m1, se1, sm1)
        ONLSTEP(a2, m2, se2, sm2) ONLSTEP(a3, m3, se3, sm3)
        ONLSTEP(b0, m0, se0, sm0) ONLSTEP(b1, m1, se1, sm1)
        ONLSTEP(b2, m2, se2, sm2) ONLSTEP(b3, m3, se3, sm3)
    }
    if (j < s1) {
        int sa = csr[j];
        size_t ba = (size_t)sa * 256 + c4;
        ushort4 ha = *(const ushort4*)(XH + ba);
        ushort4 la = *(const ushort4*)(XL + ba);
        float a0 = bf2f(ha.x) + bf2f(la.x), a1 = bf2f(ha.y) + bf2f(la.y);
        float a2 = bf2f(ha.z) + bf2f(la.z), a3 = bf2f(ha.w) + bf2f(la.w);
        ONLSTEP(a0, m0, se0, sm0) ONLSTEP(a1, m1, se1, sm1)
        ONLSTEP(a2, m2, se2, sm2) ONLSTEP(a3, m3, se3, sm3)
    }
#undef ONLSTEP
    float o0 = (s1 > s0) ? sm0 / se0 : 0.f;
    float o1 = (s1 > s0) ? sm1 / se1 : 0.f;
    float o2 = (s1 > s0) ? sm2 / se2 : 0.f;
    float o3 = (s1 > s0) ? sm3 / se3 : 0.f;
    ushort4 h, l;
    h.x = f2bf(o0); l.x = f2bf(o0 - bf2f(h.x));
    h.y = f2bf(o1); l.y = f2bf(o1 - bf2f(h.y));
    h.z = f2bf(o2); l.z = f2bf(o2 - bf2f(h.z));
    h.w = f2bf(o3); l.w = f2bf(o3 - bf2f(h.w));
    size_t ob = (size_t)node * 256 + c4;
    *(ushort4*)(OH + ob) = h;
    *(ushort4*)(OL + ob) = l;
}

// ---------------- split-bf16 MFMA GEMM, global_load_lds staging ----------------
// C = act([A1|A2] @ [W1;W2] + bias). A planes [M_pad][K] hi/lo bf16; W planes
// [N][K] hi/lo. Tile 128x128, BK=32, 4 waves. 3-term: AhBh + AhBl + AlBh.
// Output: hi/lo planes (relu) or fp32 (tanh) when Cf != nullptr.

__global__ __launch_bounds__(256)
void gemm_mfma_kernel(const ushort* __restrict__ A1H, const ushort* __restrict__ A1L, int K1,
                      const ushort* __restrict__ A2H, const ushort* __restrict__ A2L, int K2,
                      const ushort* __restrict__ B1H, const ushort* __restrict__ B1L,
                      const ushort* __restrict__ B2H, const ushort* __restrict__ B2L,
                      const float* __restrict__ bias,
                      ushort* __restrict__ CH, ushort* __restrict__ CL,
                      float* __restrict__ Cf,
                      int M, int N) {
    __shared__ __align__(16) ushort AsH[4][128][8];
    __shared__ __align__(16) ushort AsL[4][128][8];
    __shared__ __align__(16) ushort BsH[4][128][8];
    __shared__ __align__(16) ushort BsL[4][128][8];

    const int tid = threadIdx.x;
    const int lane = tid & 63;
    const int w = tid >> 6;          // wave id == staged k-group
    const int wm = w >> 1, wn = w & 1;
    const int li = lane & 15, kg = lane >> 4;
    const int bm = blockIdx.y * 128;
    const int bn = blockIdx.x * 128;

    f32x4 acc[4][4] = {};
    const int Kt = K1 + K2;

    for (int k0 = 0; k0 < Kt; k0 += 32) {
        const ushort *AH, *AL, *BH, *BL; int Ks, kk;
        if (k0 < K1) { AH = A1H; AL = A1L; BH = B1H; BL = B1L; Ks = K1; kk = k0; }
        else         { AH = A2H; AL = A2L; BH = B2H; BL = B2L; Ks = K2; kk = k0 - K1; }
        const int koff = kk + w * 8;
        const size_t ra0 = (size_t)(bm + lane) * Ks + koff;
        const size_t ra1 = (size_t)(bm + 64 + lane) * Ks + koff;
        const size_t rb0 = (size_t)(bn + lane) * Ks + koff;
        const size_t rb1 = (size_t)(bn + 64 + lane) * Ks + koff;
        gload16(AH + ra0, &AsH[w][lane][0]);
        gload16(AH + ra1, &AsH[w][64 + lane][0]);
        gload16(AL + ra0, &AsL[w][lane][0]);
        gload16(AL + ra1, &AsL[w][64 + lane][0]);
        gload16(BH + rb0, &BsH[w][lane][0]);
        gload16(BH + rb1, &BsH[w][64 + lane][0]);
        gload16(BL + rb0, &BsL[w][lane][0]);
        gload16(BL + rb1, &BsL[w][64 + lane][0]);
        __syncthreads();

        s8v ah[4], al[4], bh[4], bl[4];
        #pragma unroll
        for (int i = 0; i < 4; ++i) {
            ah[i] = *(const s8v*)&AsH[kg][wm * 64 + i * 16 + li][0];
            al[i] = *(const s8v*)&AsL[kg][wm * 64 + i * 16 + li][0];
            bh[i] = *(const s8v*)&BsH[kg][wn * 64 + i * 16 + li][0];
            bl[i] = *(const s8v*)&BsL[kg][wn * 64 + i * 16 + li][0];
        }
        #pragma unroll
        for (int i = 0; i < 4; ++i)
            #pragma unroll
            for (int j = 0; j < 4; ++j) {
                acc[i][j] = __builtin_amdgcn_mfma_f32_16x16x32_bf16(ah[i], bh[j], acc[i][j], 0, 0, 0);
                acc[i][j] = __builtin_amdgcn_mfma_f32_16x16x32_bf16(ah[i], bl[j], acc[i][j], 0, 0, 0);
                acc[i][j] = __builtin_amdgcn_mfma_f32_16x16x32_bf16(al[i], bh[j], acc[i][j], 0, 0, 0);
            }
        __syncthreads();
    }

    // epilogue. C frag: col = lane&15, row = (lane>>4)*4 + reg
    if (Cf) {
        #pragma unroll
        for (int j = 0; j < 4; ++j) {
            int col = bn + wn * 64 + j * 16 + li;
            float b = bias[col];
            #pragma unroll
            for (int i = 0; i < 4; ++i) {
                int row0 = bm + wm * 64 + i * 16 + kg * 4;
                #pragma unroll
                for (int r = 0; r < 4; ++r) {
                    int row = row0 + r;
                    if (row < M) Cf[(size_t)row * N + col] = tanhf(acc[i][j][r] + b);
                }
            }
        }
    } else {
        #pragma unroll
        for (int j = 0; j < 4; ++j) {
            int col = bn + wn * 64 + j * 16 + li;
            float b = bias[col];
            #pragma unroll
            for (int i = 0; i < 4; ++i) {
                int row0 = bm + wm * 64 + i * 16 + kg * 4;
                #pragma unroll
                for (int r = 0; r < 4; ++r) {
                    int row = row0 + r;
                    if (row < M) {
                        float v = fmaxf(acc[i][j][r] + b, 0.f);
                        ushort hi = f2bf(v);
                        size_t idx = (size_t)row * N + col;
                        CH[idx] = hi;
                        CL[idx] = f2bf(v - bf2f(hi));
                    }
                }
            }
        }
    }
}

// ---------------- launch ----------------

extern "C" void kernel_launch(void* const* d_in, const int* in_sizes, int n_in,
                              void* d_out, int out_size, void* d_ws, size_t ws_size,
                              hipStream_t stream) {
    const float* feat = (const float*)d_in[0];
    const int* einfo = (const int*)d_in[1];
    const float* b1 = (const float*)d_in[3];
    const float* b2 = (const float*)d_in[5];
    const float* b3 = (const float*)d_in[7];
    const float* bl1 = (const float*)d_in[9];
    const float* blH = (const float*)d_in[12];
    const float* bl2 = (const float*)d_in[15];
    const float* bp1 = (const float*)d_in[18];
    const float* bp2 = (const float*)d_in[20];
    const float* bp3 = (const float*)d_in[22];

    const int IN_DIM = 512, HID = 256, OUT = 128;
    const int N = in_sizes[0] / IN_DIM;   // 50000
    const int E = in_sizes[1] / 2;        // 400000
    const int* src = einfo;
    const int* dst = einfo + E;
    const int M_pad = ((N + 127) / 128) * 128;      // 50048
    const size_t PLANE = (size_t)M_pad * HID;       // 12,812,288 ushorts

    ushort* ws16 = (ushort*)d_ws;
    ushort* bufA_H = ws16;
    ushort* bufA_L = bufA_H + PLANE;
    ushort* featH  = bufA_L + PLANE;                // [M_pad][512]
    ushort* featL  = featH + 2 * PLANE;
    // aliases (feat region dead after GEMM1):
    ushort* bufB_H = featH;
    ushort* bufB_L = featH + PLANE;
    ushort* bufC_H = featH + 2 * PLANE;             // == featL
    ushort* bufC_L = featH + 3 * PLANE;
    ushort* wsp = featH + 4 * PLANE;

    // weight table
    const int widx[12] = {2, 4, 6, 8, 10, 11, 13, 14, 16, 17, 19, 21};
    const int wK[12] = {512, 256, 256, 256, 256, 256, 256, 256, 256, 256, 256, 256};
    const int wN[12] = {256, 256, 256, 256, 256, 256, 256, 256, 256, 256, 256, 128};

    PrepArgs pa;
    ushort* Hp[12]; ushort* Lp[12];
    int acc_end = 0;
    ushort* cur = wsp;
    for (int i = 0; i < 12; ++i) {
        int elems = wK[i] * wN[i];
        pa.W[i] = (const float*)d_in[widx[i]];
        Hp[i] = cur; cur += elems;
        Lp[i] = cur; cur += elems;
        pa.H[i] = Hp[i];
        pa.L[i] = Lp[i];
        acc_end += elems;
        pa.end[i] = acc_end;
        pa.Kv[i] = wK[i];
        pa.nshift[i] = (wN[i] == 256) ? 8 : 7;
    }

    int* ioff = (int*)(cur + (acc_end & 1));   // 4B-align (acc_end is even anyway)
    int* icnt = ioff + (N + 1);
    int* icur = icnt + N;
    int* csr = icur + N;

    // CSR build
    hipMemsetAsync(icnt, 0, (size_t)N * sizeof(int), stream);
    hipMemsetAsync(icur, 0, (size_t)N * sizeof(int), stream);
    hist_kernel<<<(E + 255) / 256, 256, 0, stream>>>(dst, icnt, E);
    scan_kernel<<<1, 1024, 0, stream>>>(icnt, ioff, N);
    scatter_kernel<<<(E + 255) / 256, 256, 0, stream>>>(src, dst, icur, ioff, csr, E);
    prep_weights<<<(acc_end + 255) / 256, 256, 0, stream>>>(pa, acc_end);
    // feat split
    int total4 = N * IN_DIM / 4;
    split_f32_kernel<<<(total4 + 255) / 256, 256, 0, stream>>>(feat, featH, featL, total4);

    auto gemm = [&](const ushort* A1H, const ushort* A1L, int K1,
                    const ushort* A2H, const ushort* A2L, int K2,
                    int w1, int w2, const float* bias,
                    ushort* CH, ushort* CL, float* Cf, int Nc) {
        dim3 g(Nc / 128, M_pad / 128);
        gemm_mfma_kernel<<<g, 256, 0, stream>>>(
            A1H, A1L, K1, A2H, A2L, K2,
            Hp[w1], Lp[w1],
            (w2 >= 0) ? Hp[w2] : nullptr, (w2 >= 0) ? Lp[w2] : nullptr,
            bias, CH, CL, Cf, N, Nc);
    };

    // MLP stem
    gemm(featH, featL, IN_DIM, nullptr, nullptr, 0, 0, -1, b1, bufA_H, bufA_L, nullptr, HID);
    gemm(bufA_H, bufA_L, HID, nullptr, nullptr, 0, 1, -1, b2, bufB_H, bufB_L, nullptr, HID);
    gemm(bufB_H, bufB_L, HID, nullptr, nullptr, 0, 2, -1, b3, bufA_H, bufA_L, nullptr, HID);

    // SAGE 1: x = bufA
    sage_aggr_kernel<<<(N + 3) / 4, 256, 0, stream>>>(bufA_H, bufA_L, csr, ioff, bufC_H, bufC_L, N);
    gemm(bufC_H, bufC_L, HID, bufA_H, bufA_L, HID, 3, 4, bl1, bufB_H, bufB_L, nullptr, HID);

    // SAGE 2: x = bufB
    sage_aggr_kernel<<<(N + 3) / 4, 256, 0, stream>>>(bufB_H, bufB_L, csr, ioff, bufC_H, bufC_L, N);
    gemm(bufC_H, bufC_L, HID, bufB_H, bufB_L, HID, 5, 6, blH, bufA_H, bufA_L, nullptr, HID);

    // SAGE 3: x = bufA
    sage_aggr_kernel<<<(N + 3) / 4, 256, 0, stream>>>(bufA_H, bufA_L, csr, ioff, bufC_H, bufC_L, N);
    gemm(bufC_H, bufC_L, HID, bufA_H, bufA_L, HID, 7, 8, bl2, bufB_H, bufB_L, nullptr, HID);

    // MLP head
    gemm(bufB_H, bufB_L, HID, nullptr, nullptr, 0, 9, -1, bp1, bufA_H, bufA_L, nullptr, HID);
    gemm(bufA_H, bufA_L, HID, nullptr, nullptr, 0, 10, -1, bp2, bufC_H, bufC_L, nullptr, HID);
    gemm(bufC_H, bufC_L, HID, nullptr, nullptr, 0, 11, -1, bp3, nullptr, nullptr, (float*)d_out, OUT);
}

// Round 4
// 1029.932 us; speedup vs baseline: 1.0205x; 1.0205x over previous
//
#include <hip/hip_runtime.h>
#include <hip/hip_bf16.h>
#include <math.h>

typedef short s8v __attribute__((ext_vector_type(8)));
typedef float f32x4 __attribute__((ext_vector_type(4)));

__device__ __forceinline__ ushort f2bf(float f) {
    __hip_bfloat16 h = __float2bfloat16(f);
    return *reinterpret_cast<ushort*>(&h);
}
__device__ __forceinline__ float bf2f(ushort u) {
    return __uint_as_float(((unsigned)u) << 16);
}
__device__ __forceinline__ void gload16(const void* g, void* l) {
    __builtin_amdgcn_global_load_lds(
        (const __attribute__((address_space(1))) void*)g,
        (__attribute__((address_space(3))) void*)l, 16, 0, 0);
}

// ---------------- CSR build ----------------

__global__ __launch_bounds__(256)
void hist_kernel(const int* __restrict__ dst, int* __restrict__ cnt, int E) {
    int e = blockIdx.x * 256 + threadIdx.x;
    if (e < E) atomicAdd(&cnt[dst[e]], 1);
}

__global__ __launch_bounds__(1024)
void scan_kernel(const int* __restrict__ cnt, int* __restrict__ off, int n) {
    __shared__ int lds[1024];
    int t = threadIdx.x;
    int chunk = (n + 1023) >> 10;
    int begin = t * chunk;
    int end = min(begin + chunk, n);
    if (end < begin) end = begin;
    int s = 0;
    for (int i = begin; i < end; ++i) s += cnt[i];
    lds[t] = s;
    __syncthreads();
    for (int d = 1; d < 1024; d <<= 1) {
        int v = (t >= d) ? lds[t - d] : 0;
        __syncthreads();
        lds[t] += v;
        __syncthreads();
    }
    int pre = (t == 0) ? 0 : lds[t - 1];
    for (int i = begin; i < end; ++i) { off[i] = pre; pre += cnt[i]; }
    if (t == 1023) off[n] = pre;
}

__global__ __launch_bounds__(256)
void scatter_kernel(const int* __restrict__ src, const int* __restrict__ dst,
                    int* __restrict__ cur, const int* __restrict__ off,
                    int* __restrict__ csr, int E) {
    int e = blockIdx.x * 256 + threadIdx.x;
    if (e < E) {
        int d = dst[e];
        int pos = off[d] + atomicAdd(&cur[d], 1);
        csr[pos] = src[e];
    }
}

// ---------------- weight prep: transpose + hi/lo bf16 split ----------------

struct PrepArgs {
    const float* W[12];
    ushort* H[12];
    ushort* L[12];
    int end[12];
    int Kv[12];
    int nshift[12];
};

__global__ __launch_bounds__(256)
void prep_weights(PrepArgs a, int total) {
    int id = blockIdx.x * 256 + threadIdx.x;
    if (id >= total) return;
    int s = 0;
    #pragma unroll
    for (int i = 0; i < 12; ++i) if (id >= a.end[i]) s = i + 1;
    int base = (s == 0) ? 0 : a.end[s - 1];
    int e = id - base;
    int K = a.Kv[s];
    int Nmask = (1 << a.nshift[s]) - 1;
    int n = e & Nmask;
    int k = e >> a.nshift[s];
    float w = a.W[s][(size_t)k * (Nmask + 1) + n];
    ushort hi = f2bf(w);
    ushort lo = f2bf(w - bf2f(hi));
    a.H[s][(size_t)n * K + k] = hi;
    a.L[s][(size_t)n * K + k] = lo;
}

// ---------------- per-dst online-softmax aggregation (hi/lo planes) ----------------

__global__ __launch_bounds__(256)
void sage_aggr_kernel(const ushort* __restrict__ XH, const ushort* __restrict__ XL,
                      const int* __restrict__ csr, const int* __restrict__ off,
                      ushort* __restrict__ OH, ushort* __restrict__ OL, int nN) {
    int node = blockIdx.x * 4 + (threadIdx.x >> 6);
    if (node >= nN) return;
    int c4 = (threadIdx.x & 63) * 4;
    int s0 = off[node], s1 = off[node + 1];
    float m0 = -INFINITY, m1 = -INFINITY, m2 = -INFINITY, m3 = -INFINITY;
    float se0 = 0, se1 = 0, se2 = 0, se3 = 0;
    float sm0 = 0, sm1 = 0, sm2 = 0, sm3 = 0;
#define ONLSTEP(vv, mm, ss, pp) { float nm = fmaxf(mm, vv); float r = __expf(mm - nm); \
    float p = __expf(vv - nm); ss = ss * r + p; pp = pp * r + p * (vv); mm = nm; }
    int j = s0;
    for (; j + 2 <= s1; j += 2) {
        int sa = csr[j], sb = csr[j + 1];
        size_t ba = (size_t)sa * 256 + c4, bb = (size_t)sb * 256 + c4;
        ushort4 ha = *(const ushort4*)(XH + ba);
        ushort4 la = *(const ushort4*)(XL + ba);
        ushort4 hb = *(const ushort4*)(XH + bb);
        ushort4 lb = *(const ushort4*)(XL + bb);
        float a0 = bf2f(ha.x) + bf2f(la.x), a1 = bf2f(ha.y) + bf2f(la.y);
        float a2 = bf2f(ha.z) + bf2f(la.z), a3 = bf2f(ha.w) + bf2f(la.w);
        float b0 = bf2f(hb.x) + bf2f(lb.x), b1 = bf2f(hb.y) + bf2f(lb.y);
        float b2 = bf2f(hb.z) + bf2f(lb.z), b3 = bf2f(hb.w) + bf2f(lb.w);
        ONLSTEP(a0, m0, se0, sm0) ONLSTEP(a1, m1, se1, sm1)
        ONLSTEP(a2, m2, se2, sm2) ONLSTEP(a3, m3, se3, sm3)
        ONLSTEP(b0, m0, se0, sm0) ONLSTEP(b1, m1, se1, sm1)
        ONLSTEP(b2, m2, se2, sm2) ONLSTEP(b3, m3, se3, sm3)
    }
    if (j < s1) {
        int sa = csr[j];
        size_t ba = (size_t)sa * 256 + c4;
        ushort4 ha = *(const ushort4*)(XH + ba);
        ushort4 la = *(const ushort4*)(XL + ba);
        float a0 = bf2f(ha.x) + bf2f(la.x), a1 = bf2f(ha.y) + bf2f(la.y);
        float a2 = bf2f(ha.z) + bf2f(la.z), a3 = bf2f(ha.w) + bf2f(la.w);
        ONLSTEP(a0, m0, se0, sm0) ONLSTEP(a1, m1, se1, sm1)
        ONLSTEP(a2, m2, se2, sm2) ONLSTEP(a3, m3, se3, sm3)
    }
#undef ONLSTEP
    float o0 = (s1 > s0) ? sm0 / se0 : 0.f;
    float o1 = (s1 > s0) ? sm1 / se1 : 0.f;
    float o2 = (s1 > s0) ? sm2 / se2 : 0.f;
    float o3 = (s1 > s0) ? sm3 / se3 : 0.f;
    ushort4 h, l;
    h.x = f2bf(o0); l.x = f2bf(o0 - bf2f(h.x));
    h.y = f2bf(o1); l.y = f2bf(o1 - bf2f(h.y));
    h.z = f2bf(o2); l.z = f2bf(o2 - bf2f(h.z));
    h.w = f2bf(o3); l.w = f2bf(o3 - bf2f(h.w));
    size_t ob = (size_t)node * 256 + c4;
    *(ushort4*)(OH + ob) = h;
    *(ushort4*)(OL + ob) = l;
}

// ---------------- split-bf16 MFMA GEMM, 2-phase double-buffered pipeline ----
// C = act([A1|A2] @ [W1;W2] + bias). Tile 128x128, BK=32, 4 waves.
// 3-term split: AhBh + AhBl + AlBh. LDS: 2 bufs x 4 planes x 8KB = 64KB.
// AFP32: A1 is fp32 (reg-staged + in-kernel split); else A planes via gload_lds.
// Schedule per step: ds_read(t) -> issue STAGE(t+1) -> MFMA(t) -> syncthreads
// (barrier's vmcnt(0) drains STAGE(t+1); latency hides under MFMA).

template<int K1, int K2, bool AFP32>
__global__ __launch_bounds__(256, 2)
void gemm_mfma(const float* __restrict__ A1f,
               const ushort* __restrict__ A1H, const ushort* __restrict__ A1L,
               const ushort* __restrict__ A2H, const ushort* __restrict__ A2L,
               const ushort* __restrict__ B1H, const ushort* __restrict__ B1L,
               const ushort* __restrict__ B2H, const ushort* __restrict__ B2L,
               const float* __restrict__ bias,
               ushort* __restrict__ CH, ushort* __restrict__ CL,
               float* __restrict__ Cf,
               int M, int N) {
    constexpr int NT = (K1 + K2) / 32;
    // [buf][plane: AH,AL,BH,BL][kg][row][8]
    __shared__ __align__(16) ushort lds[2][4][4][128][8];

    const int tid = threadIdx.x;
    const int lane = tid & 63;
    const int w = tid >> 6;
    const int wm = w >> 1, wn = w & 1;
    const int li = lane & 15, kg = lane >> 4;
    const int bm = blockIdx.y * 128;
    const int bn = blockIdx.x * 128;

    f32x4 acc[4][4] = {};

    auto stage_bf16 = [&](int t, int nb) {
        const ushort *AH, *AL, *BH, *BL; int Ks, kk;
        if (t * 32 < K1) { AH = A1H; AL = A1L; BH = B1H; BL = B1L; Ks = K1; kk = t * 32; }
        else             { AH = A2H; AL = A2L; BH = B2H; BL = B2L; Ks = K2; kk = t * 32 - K1; }
        int koff = kk + w * 8;
        size_t ra0 = (size_t)(bm + lane) * Ks + koff;
        size_t ra1 = ra0 + (size_t)64 * Ks;
        size_t rb0 = (size_t)(bn + lane) * Ks + koff;
        size_t rb1 = rb0 + (size_t)64 * Ks;
        gload16(AH + ra0, &lds[nb][0][w][lane][0]);
        gload16(AH + ra1, &lds[nb][0][w][64 + lane][0]);
        gload16(AL + ra0, &lds[nb][1][w][lane][0]);
        gload16(AL + ra1, &lds[nb][1][w][64 + lane][0]);
        gload16(BH + rb0, &lds[nb][2][w][lane][0]);
        gload16(BH + rb1, &lds[nb][2][w][64 + lane][0]);
        gload16(BL + rb0, &lds[nb][3][w][lane][0]);
        gload16(BL + rb1, &lds[nb][3][w][64 + lane][0]);
    };

    auto stage_B_only = [&](int t, int nb) {
        int koff = t * 32 + w * 8;
        size_t rb0 = (size_t)(bn + lane) * K1 + koff;
        size_t rb1 = rb0 + (size_t)64 * K1;
        gload16(B1H + rb0, &lds[nb][2][w][lane][0]);
        gload16(B1H + rb1, &lds[nb][2][w][64 + lane][0]);
        gload16(B1L + rb0, &lds[nb][3][w][lane][0]);
        gload16(B1L + rb1, &lds[nb][3][w][64 + lane][0]);
    };

    auto load_A = [&](int t, float4* f) {
        int gm = bm + (tid >> 1);
        const float* p = A1f + (size_t)gm * K1 + t * 32 + (tid & 1) * 16;
        if (gm < M) {
            f[0] = *(const float4*)(p);
            f[1] = *(const float4*)(p + 4);
            f[2] = *(const float4*)(p + 8);
            f[3] = *(const float4*)(p + 12);
        } else {
            f[0] = f[1] = f[2] = f[3] = make_float4(0.f, 0.f, 0.f, 0.f);
        }
    };

    auto write_A = [&](int nb, const float4* f) {
        int sm = tid >> 1, kga = (tid & 1) * 2;
        float v[16] = {f[0].x, f[0].y, f[0].z, f[0].w, f[1].x, f[1].y, f[1].z, f[1].w,
                       f[2].x, f[2].y, f[2].z, f[2].w, f[3].x, f[3].y, f[3].z, f[3].w};
        s8v h0, h1, l0, l1;
        #pragma unroll
        for (int e = 0; e < 8; ++e) {
            ushort h = f2bf(v[e]);
            h0[e] = (short)h;
            l0[e] = (short)f2bf(v[e] - bf2f(h));
        }
        #pragma unroll
        for (int e = 0; e < 8; ++e) {
            ushort h = f2bf(v[8 + e]);
            h1[e] = (short)h;
            l1[e] = (short)f2bf(v[8 + e] - bf2f(h));
        }
        *(s8v*)&lds[nb][0][kga][sm][0]     = h0;
        *(s8v*)&lds[nb][0][kga + 1][sm][0] = h1;
        *(s8v*)&lds[nb][1][kga][sm][0]     = l0;
        *(s8v*)&lds[nb][1][kga + 1][sm][0] = l1;
    };

    if constexpr (!AFP32) {
        stage_bf16(0, 0);
        __syncthreads();
        #pragma unroll
        for (int t = 0; t < NT; ++t) {
            const int cur = t & 1;
            s8v ah[4], al[4], bh[4], bl[4];
            #pragma unroll
            for (int i = 0; i < 4; ++i) {
                ah[i] = *(const s8v*)&lds[cur][0][kg][wm * 64 + i * 16 + li][0];
                al[i] = *(const s8v*)&lds[cur][1][kg][wm * 64 + i * 16 + li][0];
                bh[i] = *(const s8v*)&lds[cur][2][kg][wn * 64 + i * 16 + li][0];
                bl[i] = *(const s8v*)&lds[cur][3][kg][wn * 64 + i * 16 + li][0];
            }
            if (t + 1 < NT) stage_bf16(t + 1, cur ^ 1);
            #pragma unroll
            for (int i = 0; i < 4; ++i)
                #pragma unroll
                for (int j = 0; j < 4; ++j) {
                    acc[i][j] = __builtin_amdgcn_mfma_f32_16x16x32_bf16(ah[i], bh[j], acc[i][j], 0, 0, 0);
                    acc[i][j] = __builtin_amdgcn_mfma_f32_16x16x32_bf16(ah[i], bl[j], acc[i][j], 0, 0, 0);
                    acc[i][j] = __builtin_amdgcn_mfma_f32_16x16x32_bf16(al[i], bh[j], acc[i][j], 0, 0, 0);
                }
            __syncthreads();
        }
    } else {
        float4 f[4];
        load_A(0, f);
        stage_B_only(0, 0);
        write_A(0, f);
        __syncthreads();
        #pragma unroll
        for (int t = 0; t < NT; ++t) {
            const int cur = t & 1;
            s8v ah[4], al[4], bh[4], bl[4];
            #pragma unroll
            for (int i = 0; i < 4; ++i) {
                ah[i] = *(const s8v*)&lds[cur][0][kg][wm * 64 + i * 16 + li][0];
                al[i] = *(const s8v*)&lds[cur][1][kg][wm * 64 + i * 16 + li][0];
                bh[i] = *(const s8v*)&lds[cur][2][kg][wn * 64 + i * 16 + li][0];
                bl[i] = *(const s8v*)&lds[cur][3][kg][wn * 64 + i * 16 + li][0];
            }
            if (t + 1 < NT) { load_A(t + 1, f); stage_B_only(t + 1, cur ^ 1); }
            #pragma unroll
            for (int i = 0; i < 4; ++i)
                #pragma unroll
                for (int j = 0; j < 4; ++j) {
                    acc[i][j] = __builtin_amdgcn_mfma_f32_16x16x32_bf16(ah[i], bh[j], acc[i][j], 0, 0, 0);
                    acc[i][j] = __builtin_amdgcn_mfma_f32_16x16x32_bf16(ah[i], bl[j], acc[i][j], 0, 0, 0);
                    acc[i][j] = __builtin_amdgcn_mfma_f32_16x16x32_bf16(al[i], bh[j], acc[i][j], 0, 0, 0);
                }
            if (t + 1 < NT) write_A(cur ^ 1, f);
            __syncthreads();
        }
    }

    // epilogue. C frag: col = lane&15, row = (lane>>4)*4 + reg
    if (Cf) {
        #pragma unroll
        for (int j = 0; j < 4; ++j) {
            int col = bn + wn * 64 + j * 16 + li;
            float b = bias[col];
            #pragma unroll
            for (int i = 0; i < 4; ++i) {
                int row0 = bm + wm * 64 + i * 16 + kg * 4;
                #pragma unroll
                for (int r = 0; r < 4; ++r) {
                    int row = row0 + r;
                    if (row < M) Cf[(size_t)row * N + col] = tanhf(acc[i][j][r] + b);
                }
            }
        }
    } else {
        #pragma unroll
        for (int j = 0; j < 4; ++j) {
            int col = bn + wn * 64 + j * 16 + li;
            float b = bias[col];
            #pragma unroll
            for (int i = 0; i < 4; ++i) {
                int row0 = bm + wm * 64 + i * 16 + kg * 4;
                #pragma unroll
                for (int r = 0; r < 4; ++r) {
                    int row = row0 + r;
                    if (row < M) {
                        float v = fmaxf(acc[i][j][r] + b, 0.f);
                        ushort hi = f2bf(v);
                        size_t idx = (size_t)row * N + col;
                        CH[idx] = hi;
                        CL[idx] = f2bf(v - bf2f(hi));
                    }
                }
            }
        }
    }
}

// ---------------- launch ----------------

extern "C" void kernel_launch(void* const* d_in, const int* in_sizes, int n_in,
                              void* d_out, int out_size, void* d_ws, size_t ws_size,
                              hipStream_t stream) {
    const float* feat = (const float*)d_in[0];
    const int* einfo = (const int*)d_in[1];
    const float* b1 = (const float*)d_in[3];
    const float* b2 = (const float*)d_in[5];
    const float* b3 = (const float*)d_in[7];
    const float* bl1 = (const float*)d_in[9];
    const float* blH = (const float*)d_in[12];
    const float* bl2 = (const float*)d_in[15];
    const float* bp1 = (const float*)d_in[18];
    const float* bp2 = (const float*)d_in[20];
    const float* bp3 = (const float*)d_in[22];

    const int IN_DIM = 512, HID = 256, OUT = 128;
    const int N = in_sizes[0] / IN_DIM;   // 50000
    const int E = in_sizes[1] / 2;        // 400000
    const int* src = einfo;
    const int* dst = einfo + E;
    const int M_pad = ((N + 127) / 128) * 128;      // 50048
    const size_t PLANE = (size_t)M_pad * HID;

    ushort* ws16 = (ushort*)d_ws;
    ushort* bufA_H = ws16;
    ushort* bufA_L = bufA_H + PLANE;
    ushort* bufB_H = bufA_L + PLANE;
    ushort* bufB_L = bufB_H + PLANE;
    ushort* bufC_H = bufB_L + PLANE;
    ushort* bufC_L = bufC_H + PLANE;
    ushort* wsp = bufC_L + PLANE;

    // weight table
    const int widx[12] = {2, 4, 6, 8, 10, 11, 13, 14, 16, 17, 19, 21};
    const int wK[12] = {512, 256, 256, 256, 256, 256, 256, 256, 256, 256, 256, 256};
    const int wN[12] = {256, 256, 256, 256, 256, 256, 256, 256, 256, 256, 256, 128};

    PrepArgs pa;
    ushort* Hp[12]; ushort* Lp[12];
    int acc_end = 0;
    ushort* cur = wsp;
    for (int i = 0; i < 12; ++i) {
        int elems = wK[i] * wN[i];
        pa.W[i] = (const float*)d_in[widx[i]];
        Hp[i] = cur; cur += elems;
        Lp[i] = cur; cur += elems;
        pa.H[i] = Hp[i];
        pa.L[i] = Lp[i];
        acc_end += elems;
        pa.end[i] = acc_end;
        pa.Kv[i] = wK[i];
        pa.nshift[i] = (wN[i] == 256) ? 8 : 7;
    }

    int* ioff = (int*)(cur);
    int* icnt = ioff + (N + 1);
    int* icur = icnt + N;
    int* csr = icur + N;

    // CSR build
    hipMemsetAsync(icnt, 0, (size_t)N * sizeof(int), stream);
    hipMemsetAsync(icur, 0, (size_t)N * sizeof(int), stream);
    hist_kernel<<<(E + 255) / 256, 256, 0, stream>>>(dst, icnt, E);
    scan_kernel<<<1, 1024, 0, stream>>>(icnt, ioff, N);
    scatter_kernel<<<(E + 255) / 256, 256, 0, stream>>>(src, dst, icur, ioff, csr, E);
    prep_weights<<<(acc_end + 255) / 256, 256, 0, stream>>>(pa, acc_end);

    dim3 g2(2, M_pad / 128);   // N=256
    dim3 g1(1, M_pad / 128);   // N=128

    // GEMM1: fp32 feat, K=512
    gemm_mfma<512, 0, true><<<g2, 256, 0, stream>>>(
        feat, nullptr, nullptr, nullptr, nullptr,
        Hp[0], Lp[0], nullptr, nullptr, b1, bufA_H, bufA_L, nullptr, N, HID);
    // GEMM2
    gemm_mfma<256, 0, false><<<g2, 256, 0, stream>>>(
        nullptr, bufA_H, bufA_L, nullptr, nullptr,
        Hp[1], Lp[1], nullptr, nullptr, b2, bufB_H, bufB_L, nullptr, N, HID);
    // GEMM3
    gemm_mfma<256, 0, false><<<g2, 256, 0, stream>>>(
        nullptr, bufB_H, bufB_L, nullptr, nullptr,
        Hp[2], Lp[2], nullptr, nullptr, b3, bufA_H, bufA_L, nullptr, N, HID);

    // SAGE 1: x = bufA
    sage_aggr_kernel<<<(N + 3) / 4, 256, 0, stream>>>(bufA_H, bufA_L, csr, ioff, bufC_H, bufC_L, N);
    gemm_mfma<256, 256, false><<<g2, 256, 0, stream>>>(
        nullptr, bufC_H, bufC_L, bufA_H, bufA_L,
        Hp[3], Lp[3], Hp[4], Lp[4], bl1, bufB_H, bufB_L, nullptr, N, HID);

    // SAGE 2: x = bufB
    sage_aggr_kernel<<<(N + 3) / 4, 256, 0, stream>>>(bufB_H, bufB_L, csr, ioff, bufC_H, bufC_L, N);
    gemm_mfma<256, 256, false><<<g2, 256, 0, stream>>>(
        nullptr, bufC_H, bufC_L, bufB_H, bufB_L,
        Hp[5], Lp[5], Hp[6], Lp[6], blH, bufA_H, bufA_L, nullptr, N, HID);

    // SAGE 3: x = bufA
    sage_aggr_kernel<<<(N + 3) / 4, 256, 0, stream>>>(bufA_H, bufA_L, csr, ioff, bufC_H, bufC_L, N);
    gemm_mfma<256, 256, false><<<g2, 256, 0, stream>>>(
        nullptr, bufC_H, bufC_L, bufA_H, bufA_L,
        Hp[7], Lp[7], Hp[8], Lp[8], bl2, bufB_H, bufB_L, nullptr, N, HID);

    // MLP head
    gemm_mfma<256, 0, false><<<g2, 256, 0, stream>>>(
        nullptr, bufB_H, bufB_L, nullptr, nullptr,
        Hp[9], Lp[9], nullptr, nullptr, bp1, bufA_H, bufA_L, nullptr, N, HID);
    gemm_mfma<256, 0, false><<<g2, 256, 0, stream>>>(
        nullptr, bufA_H, bufA_L, nullptr, nullptr,
        Hp[10], Lp[10], nullptr, nullptr, bp2, bufC_H, bufC_L, nullptr, N, HID);
    gemm_mfma<256, 0, false><<<g1, 256, 0, stream>>>(
        nullptr, bufC_H, bufC_L, nullptr, nullptr,
        Hp[11], Lp[11], nullptr, nullptr, bp3, nullptr, nullptr, (float*)d_out, N, OUT);
}